// Round 2
// baseline (4385.040 us; speedup 1.0000x reference)
//
#include <hip/hip_runtime.h>
#include <stdint.h>

// ---------------------------------------------------------------------------
// DynResNet: u,v are (provably) constant; s += H*u^T dY v; x = u s v^T.
// Per step: Y = X*W^T (bf16 MFMA GEMM, W streamed via global_load_lds),
// then per-sample MFMA chain R=dY*v, dS=u^T R, inc=u*dS*v^T, x += H*inc (fp32 regs).
// Outputs are FP32 (reference dtype).
// ---------------------------------------------------------------------------

#define H_STEP 0.001f

typedef float  f32x4  __attribute__((ext_vector_type(4)));
typedef __bf16 bf16x8 __attribute__((ext_vector_type(8)));

__device__ __forceinline__ unsigned short f2bf(float f){
  unsigned u = __float_as_uint(f);
  u += 0x7FFFu + ((u >> 16) & 1u);        // RNE (finite data only)
  return (unsigned short)(u >> 16);
}
__device__ __forceinline__ float bf2f(unsigned short h){
  return __uint_as_float(((unsigned)h) << 16);
}

// W tiling: 33 layers x 50 chunks; chunk = [416 n][40 k] bf16 (32 real k + 8 pad)
#define CHUNK_ROWS 416
#define CHUNK_RB   40
#define CHUNK_ELEMS (CHUNK_ROWS*CHUNK_RB)        // 16640
#define CHUNK_BYTES (CHUNK_ELEMS*2)              // 33280
#define NCHUNKS 50
#define NLAYER  33
#define WT_ELEMS ((size_t)NLAYER*NCHUNKS*CHUNK_ELEMS)
#define WT_BYTES (WT_ELEMS*2)                    // 54,912,000
#define TR_BYTES ((size_t)NLAYER*2048*784*2)     // 105,971,712

// LDS byte offsets (total 154,880 <= 163,840)
#define WBUF0_B 0          // 34,816 (W stage buf A; dY [16][28][32] bf16 aliases; init scratch)
#define WBUF1_B 34816      // 34,816 (W stage buf B; RT [16][16][40] + G1 [16][28][16] alias)
#define XB_B    69632      // [16][808] bf16 GEMM A (x), K padded to 800
#define UA_B    95488      // [16][28][16] bf16  u[i][a]    (A for G1)
#define UA2_B   109824     // [16][10][40] bf16  u^T[a][i]  (A for dS)
#define VB2_B   122624     // [16][10][40] bf16  vh[b][j]   (B for R)
#define VTB_B   135424     // [16][28][16] bf16  v[j][b]    (B for G2)
#define DSB_B   149760     // [16][10][16] bf16  dS^T[b][a] (B for G1); logits scratch
#define LDS_TOTAL 154880
#define RT_B (WBUF1_B)
#define G1_B (WBUF1_B + 20480)

__device__ __forceinline__ void gl16(const void* g, void* l){
  __builtin_amdgcn_global_load_lds(
      (const __attribute__((address_space(1))) unsigned int*)g,
      (__attribute__((address_space(3))) unsigned int*)l, 16, 0, 0);
}

// ---------------- prep: tile W0/Ws into bf16 B-fragment layout ----------------
__global__ void dyn_prep(const float* __restrict__ W0, const float* __restrict__ Ws,
                         unsigned short* __restrict__ WT)
{
  const int total = NLAYER*NCHUNKS*CHUNK_ELEMS;
  for (int e = blockIdx.x*256 + threadIdx.x; e < total; e += gridDim.x*256){
    int c   = e / CHUNK_ELEMS;
    int off = e - c*CHUNK_ELEMS;
    int n_  = off / CHUNK_RB;
    int kk  = off - n_*CHUNK_RB;
    int l   = c / NCHUNKS;
    int r   = c - l*NCHUNKS;
    int nh  = r / 25;
    int kc  = r - nh*25;
    int n   = nh*416 + n_;
    int qk  = kc*32 + kk;
    float v = 0.f;
    if (kk < 32 && n < 784 && qk < 784){
      const float* W = (l == 0) ? W0 : (Ws + (size_t)(l-1)*614656);
      v = W[(size_t)n*784 + qk];
    }
    WT[e] = f2bf(v);
  }
}

// ---------------- main persistent kernel ----------------
__global__ void __launch_bounds__(256,1)
dyn_net(const float* __restrict__ X, const float* __restrict__ bs,
        const float* __restrict__ Wc, const float* __restrict__ bc,
        const unsigned short* __restrict__ WT,
        unsigned short* __restrict__ TR, float* __restrict__ OUT, int use_tr)
{
  extern __shared__ char smem[];
  unsigned short* s16 = (unsigned short*)smem;
  const int tid = threadIdx.x;
  const int w = tid >> 6, lane = tid & 63, quad = lane >> 4, col = lane & 15;
  const int blk = blockIdx.x;

  for (int i = tid; i < LDS_TOTAL/4; i += 256) ((unsigned int*)smem)[i] = 0u;
  __syncthreads();

  // static per-sample operand buffers (u,v never change)
  for (int e = tid; e < 16*28*16; e += 256){            // uA [m][i][a16]
    int m = e / 448, r = e % 448, i = r >> 4, a = r & 15;
    float v = (a < 10) ? X[(size_t)(blk*16+m)*840 + i*10 + a] : 0.f;
    s16[UA_B/2 + e] = f2bf(v);
  }
  for (int e = tid; e < 16*10*40; e += 256){            // uA2 [m][a][i40]
    int m = e / 400, r = e % 400, a = r / 40, i = r % 40;
    float v = (i < 28) ? X[(size_t)(blk*16+m)*840 + i*10 + a] : 0.f;
    s16[UA2_B/2 + e] = f2bf(v);
  }
  for (int e = tid; e < 16*10*40; e += 256){            // vB2 [m][b][j40] = vh[b][j]
    int m = e / 400, r = e % 400, b = r / 40, j = r % 40;
    float v = (j < 28) ? X[(size_t)(blk*16+m)*840 + 560 + b*28 + j] : 0.f;
    s16[VB2_B/2 + e] = f2bf(v);
  }
  for (int e = tid; e < 16*28*16; e += 256){            // vTB [m][j][b16] = vh[b][j]
    int m = e / 448, r = e % 448, j = r >> 4, b = r & 15;
    float v = (b < 10) ? X[(size_t)(blk*16+m)*840 + 560 + b*28 + j] : 0.f;
    s16[VTB_B/2 + e] = f2bf(v);
  }
  __syncthreads();

  // x_init = u*s0*vh in exact fp32; xr = register fp32 x master
  float xr[4][2][2][4];
  for (int q = 0; q < 4; ++q){
    int m = w*4 + q;
    int gm = blk*16 + m;
    float* scr = (float*)(smem + WBUF0_B) + w*2048;     // 8KB/wave scratch
    for (int e = lane; e < 840; e += 64) scr[e] = X[(size_t)gm*840 + e];
    __syncthreads();
    float* T = scr + 840;                               // T = u@s0 (28x10)
    for (int it = 0; it < 5; ++it){
      int e = lane + it*64;
      if (e < 280){
        int i = e / 10, b = e % 10;
        float acc = 0.f;
        for (int a = 0; a < 10; ++a) acc += scr[i*10+a] * scr[280 + a*10 + b];
        T[e] = acc;
      }
    }
    __syncthreads();
    #pragma unroll
    for (int mt = 0; mt < 2; ++mt)
    #pragma unroll
    for (int nt = 0; nt < 2; ++nt)
    #pragma unroll
    for (int r = 0; r < 4; ++r){
      int i = mt*16 + quad*4 + r;
      int j = nt*16 + col;
      float acc = 0.f;
      if (i < 28 && j < 28){
        for (int b = 0; b < 10; ++b) acc += T[i*10+b] * scr[560 + b*28 + j];
        s16[XB_B/2 + m*808 + i*28 + j] = f2bf(acc);
      }
      xr[q][mt][nt][r] = acc;
    }
    __syncthreads();
  }

  const int cnt0  = (w < 2) ? 7 : 6;                    // n-tiles per wave per half
  const int tbase = (w==0) ? 0 : (w==1) ? 7 : (w==2) ? 14 : 20;
  const float Hs = H_STEP;

  for (int t = 0; t < NLAYER; ++t){
    const unsigned short* WL = WT + (size_t)t*NCHUNKS*CHUNK_ELEMS;
    f32x4 acc[2][7];
    #pragma unroll
    for (int h = 0; h < 2; ++h)
      #pragma unroll
      for (int p = 0; p < 7; ++p) acc[h][p] = (f32x4){0.f,0.f,0.f,0.f};

    // prologue: stage chunk 0 -> buf0
    {
      const char* g = (const char*)WL;
      char* l = smem + WBUF0_B;
      #pragma unroll
      for (int rnd = 0; rnd < 8; ++rnd)
        gl16(g + rnd*4096 + w*1024 + lane*16, l + rnd*4096 + w*1024);
      if (tid < 32) gl16(g + 32768 + lane*16, l + 32768);
    }

    #pragma unroll 1
    for (int nh = 0; nh < 2; ++nh){
      #pragma unroll 1
      for (int kc = 0; kc < 25; ++kc){
        int c = nh*25 + kc;
        __syncthreads();                                // stage(c) drained; prev compute done
        if (c < 49){
          int c1 = c + 1;
          const char* g = (const char*)(WL + (size_t)c1*CHUNK_ELEMS);
          char* l = smem + ((c1 & 1) ? WBUF1_B : WBUF0_B);
          #pragma unroll
          for (int rnd = 0; rnd < 8; ++rnd)
            gl16(g + rnd*4096 + w*1024 + lane*16, l + rnd*4096 + w*1024);
          if (tid < 32) gl16(g + 32768 + lane*16, l + 32768);
        }
        const unsigned short* wb =
            (const unsigned short*)(smem + ((c & 1) ? WBUF1_B : WBUF0_B));
        bf16x8 afrag = *(const bf16x8*)(s16 + XB_B/2 + col*808 + kc*32 + quad*8);
        #pragma unroll
        for (int p = 0; p < 7; ++p){
          if (p < cnt0){
            int nloc = (tbase + p)*16 + col;
            bf16x8 bfrag = *(const bf16x8*)(wb + nloc*40 + quad*8);
            acc[nh][p] = __builtin_amdgcn_mfma_f32_16x16x32_bf16(afrag, bfrag, acc[nh][p], 0,0,0);
          }
        }
      }
    }

    // epilogue: bias/relu, write dY bf16 into WBUF0
    unsigned short* dy = (unsigned short*)(smem + WBUF0_B);
    #pragma unroll 1
    for (int nh = 0; nh < 2; ++nh){
      #pragma unroll
      for (int p = 0; p < 7; ++p){
        if (p < cnt0){
          int n = nh*416 + (tbase+p)*16 + col;
          if (n < 784){
            int i = n / 28, j = n % 28;
            float bias = (t > 0) ? bs[(size_t)(t-1)*784 + n] : 0.f;
            #pragma unroll
            for (int r = 0; r < 4; ++r){
              float y = acc[nh][p][r] + bias;
              if (t > 0) y = fmaxf(y, 0.f);
              int m = quad*4 + r;
              dy[m*896 + i*32 + j] = f2bf(y);
            }
          }
        }
      }
    }
    __syncthreads();                                    // dY visible to all waves

    // small stages per wave (samples w*4..w*4+3)
    #pragma unroll 1
    for (int q = 0; q < 4; ++q){
      int m = w*4 + q;
      bf16x8 zfrag = {0,0,0,0,0,0,0,0};
      const unsigned short* dys = dy + m*896;
      // R = dY @ v  -> RT[b][i]
      bf16x8 bfA = zfrag;
      if (col < 10) bfA = *(const bf16x8*)(s16 + VB2_B/2 + m*400 + col*40 + quad*8);
      unsigned short* rt = s16 + RT_B/2 + m*640;
      #pragma unroll
      for (int mt = 0; mt < 2; ++mt){
        bf16x8 afA = *(const bf16x8*)(dys + (col + 16*mt)*32 + quad*8);
        f32x4 cR = {0.f,0.f,0.f,0.f};
        cR = __builtin_amdgcn_mfma_f32_16x16x32_bf16(afA, bfA, cR, 0,0,0);
        int i0 = mt*16 + quad*4;
        if (i0 < 28){
          unsigned short* p = rt + col*40 + i0;
          p[0]=f2bf(cR[0]); p[1]=f2bf(cR[1]); p[2]=f2bf(cR[2]); p[3]=f2bf(cR[3]);
        }
      }
      // dS = u^T @ R
      bf16x8 afB = zfrag;
      if (col < 10) afB = *(const bf16x8*)(s16 + UA2_B/2 + m*400 + col*40 + quad*8);
      bf16x8 bfB = *(const bf16x8*)(rt + col*40 + quad*8);
      f32x4 cS = {0.f,0.f,0.f,0.f};
      cS = __builtin_amdgcn_mfma_f32_16x16x32_bf16(afB, bfB, cS, 0,0,0);
      unsigned short* dsb = s16 + DSB_B/2 + m*160;      // dS^T[b][a]
      if (col < 10){
        unsigned short* p = dsb + col*16 + quad*4;
        p[0]=f2bf(cS[0]); p[1]=f2bf(cS[1]); p[2]=f2bf(cS[2]); p[3]=f2bf(cS[3]);
      }
      // G1 = u @ dS  (K=16 via quads 0,1)
      bf16x8 bfG = zfrag;
      if (quad < 2 && col < 10) bfG = *(const bf16x8*)(dsb + col*16 + quad*8);
      const unsigned short* ua = s16 + UA_B/2 + m*448;
      unsigned short* g1 = s16 + G1_B/2 + m*448;
      #pragma unroll
      for (int mt = 0; mt < 2; ++mt){
        int row = col + 16*mt;
        bf16x8 afG = zfrag;
        if (quad < 2 && row < 28) afG = *(const bf16x8*)(ua + row*16 + quad*8);
        f32x4 cG = {0.f,0.f,0.f,0.f};
        cG = __builtin_amdgcn_mfma_f32_16x16x32_bf16(afG, bfG, cG, 0,0,0);
        int i0 = mt*16 + quad*4;
        #pragma unroll
        for (int r = 0; r < 4; ++r)
          if (i0 + r < 28) g1[(i0+r)*16 + col] = f2bf(cG[r]);
      }
      // G2 = G1 @ v^T ; x += H*G2 (fp32 regs); write xb + transformed output
      const unsigned short* vtb = s16 + VTB_B/2 + m*448;
      bf16x8 bt[2];
      #pragma unroll
      for (int nt = 0; nt < 2; ++nt){
        bt[nt] = zfrag;
        int n = col + 16*nt;
        if (quad < 2 && n < 28) bt[nt] = *(const bf16x8*)(vtb + n*16 + quad*8);
      }
      int gm = blk*16 + m;
      #pragma unroll
      for (int mt = 0; mt < 2; ++mt){
        int row = col + 16*mt;
        bf16x8 afX = zfrag;
        if (quad < 2 && row < 28) afX = *(const bf16x8*)(g1 + row*16 + quad*8);
        #pragma unroll
        for (int nt = 0; nt < 2; ++nt){
          f32x4 cX = {0.f,0.f,0.f,0.f};
          cX = __builtin_amdgcn_mfma_f32_16x16x32_bf16(afX, bt[nt], cX, 0,0,0);
          int i0 = mt*16 + quad*4;
          int j = nt*16 + col;
          if (j < 28){
            #pragma unroll
            for (int r = 0; r < 4; ++r){
              int i = i0 + r;
              if (i < 28){
                float xn = xr[q][mt][nt][r] + Hs * cX[r];
                xr[q][mt][nt][r] = xn;
                unsigned short hb = f2bf(xn);
                s16[XB_B/2 + m*808 + i*28 + j] = hb;
                if (use_tr) TR[((size_t)t*2048 + gm)*784 + i*28 + j] = hb;
                else OUT[40960 + ((size_t)gm*784 + i*28 + j)*33 + t] = xn;
              }
            }
          }
        }
      }
    }
    __syncthreads();                                    // step end
  }

  // classifier + softmax (fp32 outputs)
  float* lg = (float*)(smem + DSB_B);
  if (tid < 160){
    int m = tid / 10, c = tid % 10;
    float accv = bc[c];
    const unsigned short* xbp = s16 + XB_B/2 + m*808;
    for (int p = 0; p < 784; ++p)
      accv += bf2f(xbp[p]) * Wc[(size_t)c*784 + p];
    lg[tid] = accv;
  }
  __syncthreads();
  if (tid < 16){
    int gm = blk*16 + tid;
    float* l = lg + tid*10;
    float mx = l[0];
    for (int c2 = 1; c2 < 10; ++c2) mx = fmaxf(mx, l[c2]);
    float s = 0.f, ex[10];
    for (int c2 = 0; c2 < 10; ++c2){ ex[c2] = expf(l[c2]-mx); s += ex[c2]; }
    float inv = 1.f / s;
    for (int c2 = 0; c2 < 10; ++c2){
      OUT[(size_t)gm*10 + c2]         = ex[c2]*inv;   // X_predicted (fp32)
      OUT[20480 + (size_t)gm*10 + c2] = l[c2];        // X_classified (fp32)
    }
  }
}

// ---------------- transpose TR[t][gm][p] -> OUT[gm][p][t] (fp32) ----------------
__global__ void dyn_transp(const unsigned short* __restrict__ TR,
                           float* __restrict__ OUT)
{
  __shared__ unsigned short tile[33][786];
  int gm = blockIdx.x, tid = threadIdx.x;
  for (int idx = tid; idx < 33*392; idx += 256){
    int t = idx / 392, pp = idx - t*392;
    unsigned int v = *(const unsigned int*)(TR + ((size_t)t*2048 + gm)*784 + pp*2);
    *(unsigned int*)(&tile[t][pp*2]) = v;
  }
  __syncthreads();
  size_t ob = 40960 + (size_t)gm*784*33;
  for (int f = tid; f < 784*33; f += 256){
    int p = f / 33, t = f - p*33;
    OUT[ob + f] = bf2f(tile[t][p]);
  }
}

// ---------------- launch ----------------
extern "C" void kernel_launch(void* const* d_in, const int* in_sizes, int n_in,
                              void* d_out, int out_size, void* d_ws, size_t ws_size,
                              hipStream_t stream)
{
  const float* X  = (const float*)d_in[0];
  const float* W0 = (const float*)d_in[1];
  const float* Ws = (const float*)d_in[2];
  const float* bs = (const float*)d_in[3];
  const float* Wc = (const float*)d_in[4];
  const float* bc = (const float*)d_in[5];
  unsigned short* WT = (unsigned short*)d_ws;
  unsigned short* TR = (unsigned short*)((char*)d_ws + WT_BYTES);
  float* OUT = (float*)d_out;
  const int use_tr = (ws_size >= (size_t)WT_BYTES + TR_BYTES) ? 1 : 0;

  (void)hipFuncSetAttribute((const void*)dyn_net,
        hipFuncAttributeMaxDynamicSharedMemorySize, LDS_TOTAL);

  dyn_prep<<<dim3(8192), dim3(256), 0, stream>>>(W0, Ws, WT);
  dyn_net<<<dim3(128), dim3(256), LDS_TOTAL, stream>>>(X, bs, Wc, bc, WT, TR, OUT, use_tr);
  if (use_tr)
    dyn_transp<<<dim3(2048), dim3(256), 0, stream>>>(TR, OUT);
}